// Round 14
// baseline (735.582 us; speedup 1.0000x reference)
//
#include <hip/hip_runtime.h>
#include <hip/hip_bf16.h>
#include <math.h>

#define BB 16
#define TT 128
#define VV 137
#define CCH 3
#define NN (VV*TT)        // 17536 spatial, v-major: n = v*128 + t
#define NCLS 226
#define APITCH 23040      // shorts per (b,t) adjacency slab: [144 w][160 v] = 45 x 1KB

typedef __attribute__((ext_vector_type(8))) short bf16x8;
typedef __attribute__((ext_vector_type(4))) float f32x4;

__device__ __forceinline__ unsigned short f2bf(float x) {
  __hip_bfloat16 h = __float2bfloat16(x);
  return *reinterpret_cast<unsigned short*>(&h);
}

// async 16B direct-to-LDS copy
__device__ __forceinline__ void gld_lds16(const unsigned short* src, unsigned short* ldst) {
  __builtin_amdgcn_global_load_lds(
      (const __attribute__((address_space(1))) void*)src,
      (__attribute__((address_space(3))) void*)ldst, 16, 0, 0);
}

// ---------------- BN stats ----------------
__global__ void bn_stats_kernel(const float* __restrict__ X,
                                const float* __restrict__ gamma,
                                const float* __restrict__ beta,
                                float* __restrict__ scale,
                                float* __restrict__ shift) {
  const int ch = blockIdx.x;           // 0..410
  const int v = ch / CCH, c = ch % CCH;
  const int tid = threadIdx.x;
  float s = 0.f, q = 0.f;
  for (int idx = tid; idx < BB*TT; idx += 256) {
    float x = X[(idx*VV + v)*CCH + c];
    s += x; q += x*x;
  }
  #pragma unroll
  for (int off = 32; off > 0; off >>= 1) {
    s += __shfl_down(s, off, 64);
    q += __shfl_down(q, off, 64);
  }
  __shared__ float ls[4], lq[4];
  const int wid = tid >> 6, lane = tid & 63;
  if (lane == 0) { ls[wid] = s; lq[wid] = q; }
  __syncthreads();
  if (tid == 0) {
    float S = ls[0]+ls[1]+ls[2]+ls[3];
    float Q = lq[0]+lq[1]+lq[2]+lq[3];
    const float inv_n = 1.f / (BB*TT);
    float mean = S * inv_n;
    float var = Q * inv_n - mean*mean;
    float sc = gamma[ch] * rsqrtf(var + 1e-5f);
    scale[ch] = sc;
    shift[ch] = beta[ch] - mean * sc;
  }
}

// ---------------- BN apply -> xn v-major [b][v*128+t][3] bf16 ----------------
__global__ void bn_apply_v(const float* __restrict__ X,
                           const float* __restrict__ scale,
                           const float* __restrict__ shift,
                           unsigned short* __restrict__ xn) {
  const int o = blockIdx.x*256 + threadIdx.x;
  if (o >= BB*NN*CCH) return;
  const int c = o % CCH;
  const int n = (o / CCH) % NN;
  const int b = o / (CCH*NN);
  const int v = n >> 7, t = n & 127;
  const int ch = v*CCH + c;
  float val = X[((b*TT + t)*VV + v)*CCH + c] * scale[ch] + shift[ch];
  xn[o] = f2bf(val);
}

// ---------------- weight transpose: w[oc][ic][9] fp32 -> wT[kk][oc][ic] bf16 ----------------
__global__ void wtrans_kernel(const float* __restrict__ w, unsigned short* __restrict__ wT,
                              int OC, int IC) {
  const int o = blockIdx.x*256 + threadIdx.x;
  if (o >= OC*IC*9) return;
  const int ic = o % IC;
  const int oc = (o / IC) % OC;
  const int kk = o / (IC*OC);
  wT[o] = f2bf(w[(oc*IC + ic)*9 + kk]);
}

// ---------------- conv0 weights: w0[64][3][9] -> w0T[64][32] ----------------
__global__ void w0trans_kernel(const float* __restrict__ w0, unsigned short* __restrict__ w0T) {
  const int o = blockIdx.x*256 + threadIdx.x;
  if (o >= 64*32) return;
  const int k = o % 32, oc = o / 32;
  const int kk = k / 3, ic = k % 3;
  w0T[o] = (k < 27) ? f2bf(w0[(oc*3 + ic)*9 + kk]) : (unsigned short)0;
}

__global__ void zero_kernel(float* __restrict__ p, int n) {
  const int i = blockIdx.x*256 + threadIdx.x;
  if (i < n) p[i] = 0.f;
}

// ---------------- adjacency precompute: slab [144][160] per (b,t), zero-padded ----------------
__global__ __launch_bounds__(256)
void adj_v(const float* __restrict__ X, unsigned short* __restrict__ A) {
  __shared__ float Xs[3][144];
  const int b = blockIdx.x / TT, t = blockIdx.x % TT;
  const int tid = threadIdx.x;
  for (int i = tid; i < 3*VV; i += 256) {
    const int c = i / VV, v = i % VV;
    Xs[c][v] = X[((b*TT + t)*VV + v)*CCH + c];
  }
  __syncthreads();
  unsigned short* Ab = A + (size_t)blockIdx.x * APITCH;
  for (int e = tid; e < 144*160; e += 256) {
    const int w = e / 160, v = e % 160;
    unsigned short val = 0;
    if (w < VV && v < VV) {
      const float d0 = Xs[0][v]-Xs[0][w];
      const float d1 = Xs[1][v]-Xs[1][w];
      const float d2 = Xs[2][v]-Xs[2][w];
      val = f2bf(__expf(-2.f * sqrtf(d0*d0 + d1*d1 + d2*d2)));
    }
    Ab[e] = val;
  }
}

// ---------------- conv0: v-major, block = one v-row (128 t), K=32 im2col ----------------
__global__ __launch_bounds__(256)
void conv0_v(const unsigned short* __restrict__ xn,   // [gb][NN][3]
             const unsigned short* __restrict__ w0T,  // [64][32]
             const float* __restrict__ bias,
             unsigned short* __restrict__ outp) {     // [gb][NN][64]
  __shared__ unsigned short im_s[128*40];
  __shared__ unsigned short w_s[64*40];
  __shared__ unsigned short ob[128*72];
  const int tid = threadIdx.x;
  const int v0 = blockIdx.x % 137;
  const int b  = blockIdx.x / 137;
  const int wave = tid >> 6, lane = tid & 63, quad = lane >> 4, l15 = lane & 15;
  const int mh = wave * 32;

  {
    const int row = tid >> 2, cg = tid & 3;
    *(uint4*)&w_s[row*40 + cg*8] = *(const uint4*)(w0T + row*32 + cg*8);
  }
  for (int e = tid; e < 128*32; e += 256) {
    const int t = e >> 5, k = e & 31;
    unsigned short val = 0;
    if (k < 27) {
      const int kk = k / 3, ic = k % 3;
      const int tp = t + kk - 4;
      if (tp >= 0 && tp < TT)
        val = xn[((size_t)b*NN + (size_t)v0*TT + tp)*3 + ic];
    }
    im_s[t*40 + k] = val;
  }
  __syncthreads();

  f32x4 acc[2][4];
  #pragma unroll
  for (int mt = 0; mt < 2; ++mt)
    #pragma unroll
    for (int ct = 0; ct < 4; ++ct) acc[mt][ct] = (f32x4){0.f,0.f,0.f,0.f};

  bf16x8 af[2], bfr[4];
  #pragma unroll
  for (int mt = 0; mt < 2; ++mt)
    af[mt] = *(const bf16x8*)&im_s[(mh + mt*16 + l15)*40 + quad*8];
  #pragma unroll
  for (int ct = 0; ct < 4; ++ct)
    bfr[ct] = *(const bf16x8*)&w_s[(ct*16 + l15)*40 + quad*8];
  #pragma unroll
  for (int mt = 0; mt < 2; ++mt)
    #pragma unroll
    for (int ct = 0; ct < 4; ++ct)
      acc[mt][ct] = __builtin_amdgcn_mfma_f32_16x16x32_bf16(af[mt], bfr[ct], acc[mt][ct], 0, 0, 0);

  #pragma unroll
  for (int mt = 0; mt < 2; ++mt) {
    const int tb = mh + mt*16 + quad*4;
    #pragma unroll
    for (int ct = 0; ct < 4; ++ct) {
      const int oc = ct*16 + l15;
      const float bv = bias[oc];
      #pragma unroll
      for (int r = 0; r < 4; ++r)
        ob[(tb + r)*72 + oc] = f2bf(acc[mt][ct][r] + bv);
    }
  }
  __syncthreads();
  for (int rr = 0; rr < 4; ++rr) {
    const int idx = rr*256 + tid;
    const int t = idx >> 3, cg = idx & 7;
    uint4 val = *(const uint4*)&ob[t*72 + cg*8];
    *(uint4*)(outp + ((size_t)b*NN + (size_t)v0*TT + t)*64 + cg*8) = val;
  }
}

// ---------------- conv v4: input in LDS (staged once), WEIGHTS IN REGISTERS ----------------
// Register software pipeline over flattened (kk,ks) K-steps: prefetch step s+2's
// B-fragments from global (L2-resident, per-wave-private) while computing step s.
// ZERO barriers in the K-loop. block = 1 v-row x OCB; wave = t-half x oc-half.
template<int IC, int OCB, int RELU, int FUSE>
__global__ __launch_bounds__(256)
void conv_v4(const unsigned short* __restrict__ in,    // [gb][NN][IC]
             const unsigned short* __restrict__ wT,    // [9][OCtot][IC]
             const float* __restrict__ bias,
             unsigned short* __restrict__ outp,        // [gb][NN][OCB] (OCtot==OCB)
             float* __restrict__ mout,
             const unsigned short* __restrict__ zbuf,
             int OCtot, int nocb) {
  constexpr int NCT  = OCB/32;              // col-tiles per wave (2 or 4)
  constexpr int KS   = IC/32;               // k-steps per kk
  constexpr int NSTEP= 9*KS;                // 18 or 36
  constexpr int NWIN = 136*IC/512;          // input 1KB windows
  constexpr int GPR  = IC/8;
  constexpr int RPW  = 512/IC;
  constexpr int INSZ = 136*IC;              // shorts
  constexpr int OCP  = OCB + 8;
  constexpr int OBSZ = FUSE ? 0 : 128*OCP;
  constexpr int TOT  = (INSZ > OBSZ) ? INSZ : OBSZ;
  __shared__ unsigned short sh[TOT];
  unsigned short* in_s = sh;
  unsigned short* ob = sh;

  const int tid = threadIdx.x;
  const int wave = tid >> 6, lane = tid & 63, quad = lane >> 4, l15 = lane & 15;
  const int v0   = blockIdx.x % 137;
  const int ocby = (blockIdx.x / 137) % nocb;
  const int b    = blockIdx.x / (137*nocb);
  const int ocb0 = ocby * OCB;
  const int mhl = (wave >> 1) * 64;          // t-half base
  const int chb = (wave & 1) * (OCB >> 1);   // oc-half base

  const int lrow = lane / GPR;
  const int lg   = lane % GPR;

  // ---- stage input once (async DMA; drained by the single barrier below) ----
  #pragma unroll
  for (int wi = 0; wi < (NWIN+3)/4; ++wi) {
    const int W = wave + 4*wi;
    if (W < NWIN) {
      const int rl = W*RPW + lrow;
      const int t = rl - 4;
      const int sg = lg ^ (rl & 7);
      const unsigned short* src = (t >= 0 && t < TT)
          ? in + ((size_t)b*NN + (size_t)v0*TT + t)*IC + (sg<<3)
          : zbuf + lane*8;
      gld_lds16(src, in_s + W*512);
    }
  }

  // ---- weight fragment loader: per-wave-private, affine address, global->VGPR ----
  const unsigned short* wbase = wT + ((size_t)(ocb0 + chb + l15))*IC + quad*8;
  auto wload = [&](int s, bf16x8 (&wr)[NCT]) {
    const int kk = s / KS, ks = s - kk*KS;
    const unsigned short* p = wbase + ((size_t)kk*OCtot)*IC + ks*32;
    #pragma unroll
    for (int ct = 0; ct < NCT; ++ct)
      wr[ct] = *(const bf16x8*)(p + ct*16*IC);
  };

  f32x4 acc[4][NCT];
  #pragma unroll
  for (int mt = 0; mt < 4; ++mt)
    #pragma unroll
    for (int ct = 0; ct < NCT; ++ct) acc[mt][ct] = (f32x4){0.f,0.f,0.f,0.f};

  auto compute_step = [&](int kk, int ks, bf16x8 (&wr)[NCT]) {
    const int G = ks*4 + quad;
    bf16x8 af[4];
    #pragma unroll
    for (int mt = 0; mt < 4; ++mt) {
      const int row = mhl + mt*16 + l15 + kk;
      af[mt] = *(const bf16x8*)&in_s[row*IC + ((G ^ (row & 7)) << 3)];
    }
    #pragma unroll
    for (int mt = 0; mt < 4; ++mt)
      #pragma unroll
      for (int ct = 0; ct < NCT; ++ct)
        acc[mt][ct] = __builtin_amdgcn_mfma_f32_16x16x32_bf16(af[mt], wr[ct], acc[mt][ct], 0, 0, 0);
  };

  // prefetch depth 2 (issued BEFORE the barrier so load latency overlaps the drain)
  bf16x8 wA[NCT], wB[NCT];
  wload(0, wA);
  wload(1, wB);
  __syncthreads();   // input DMA drained; the ONLY barrier before the epilogue

  #pragma unroll
  for (int s = 0; s < NSTEP; s += 2) {
    compute_step(s / KS, s % KS, wA);
    if (s + 2 < NSTEP) wload(s + 2, wA);
    compute_step((s+1) / KS, (s+1) % KS, wB);
    if (s + 3 < NSTEP) wload(s + 3, wB);
  }

  if (FUSE) {
    #pragma unroll
    for (int ct = 0; ct < NCT; ++ct) {
      const int oc = ocb0 + chb + ct*16 + l15;
      const float bv = bias[oc];
      float s = 0.f;
      #pragma unroll
      for (int mt = 0; mt < 4; ++mt)
        #pragma unroll
        for (int r = 0; r < 4; ++r) {
          float x = acc[mt][ct][r] + bv;
          if (RELU) x = fmaxf(x, 0.f);
          s += x;
        }
      s += __shfl_down(s, 32, 64);
      s += __shfl_down(s, 16, 64);
      if (lane < 16) atomicAdd(&mout[(size_t)b*OCtot + oc], s * (1.f / NN));
    }
  } else {
    __syncthreads();   // all in_s reads complete before ob (alias) is written
    #pragma unroll
    for (int mt = 0; mt < 4; ++mt) {
      const int ro = mhl + mt*16 + quad*4;
      #pragma unroll
      for (int ct = 0; ct < NCT; ++ct) {
        const int oc = chb + ct*16 + l15;
        const float bv = bias[ocb0 + oc];
        #pragma unroll
        for (int r = 0; r < 4; ++r) {
          float x = acc[mt][ct][r] + bv;
          if (RELU) x = fmaxf(x, 0.f);
          ob[(ro + r)*OCP + oc] = f2bf(x);
        }
      }
    }
    __syncthreads();
    constexpr int GPO = OCB/8;
    #pragma unroll
    for (int it = 0; it < 128*GPO/256; ++it) {
      const int task = it*256 + tid;
      const int ro = task / GPO, g = task % GPO;
      uint4 val = *(const uint4*)&ob[ro*OCP + g*8];
      *(uint4*)(outp + ((size_t)b*NN + (size_t)v0*TT + ro)*OCB + g*8) = val;
    }
  }
}

// ---------------- graph matmul v3: adjacency DMA'd into LDS, ob aliased over As ----------------
__global__ __launch_bounds__(256)
void gmm_v3(const unsigned short* __restrict__ A,     // [gb*T][APITCH]
            const unsigned short* __restrict__ act,
            unsigned short* __restrict__ outp,
            int Cfull) {
  __shared__ unsigned short sh[12288 + APITCH];
  unsigned short* xt = sh;            // X^T[c][v granule-swizzled], 64*192
  unsigned short* As = sh + 12288;    // [144 w][160 v]
  unsigned short* ob = sh + 12288;    // aliases As after compute barrier
  const int bt = blockIdx.x;
  const int b = bt / TT, t = bt % TT;
  const int ch = blockIdx.y;
  const int tid = threadIdx.x;
  const int wave = tid >> 6, lane = tid & 63, quad = lane >> 4, l15 = lane & 15;

  const unsigned short* Abt = A + (size_t)bt * APITCH;
  for (int W = wave; W < 45; W += 4)
    gld_lds16(Abt + W*512 + lane*8, As + W*512);

  #pragma unroll
  for (int it = 0; it < 5; ++it) {
    const int task = it*256 + tid;
    const int v = task >> 3, g = task & 7;
    uint4 val = {0u,0u,0u,0u};
    if (v < VV)
      val = *(const uint4*)(act + ((size_t)b*NN + (size_t)v*TT + t)*Cfull + ch*64 + g*8);
    const unsigned short* pv = (const unsigned short*)&val;
    const int vg = v >> 3, vrm = v & 7;
    #pragma unroll
    for (int j = 0; j < 8; ++j) {
      const int c = g*8 + j;
      const int slot = ((vg ^ (c & 7) ^ ((c >> 3) & 7)) << 3) | vrm;
      xt[c*192 + slot] = pv[j];
    }
  }
  __syncthreads();

  f32x4 acc[9];
  #pragma unroll
  for (int ct = 0; ct < 9; ++ct) acc[ct] = (f32x4){0.f,0.f,0.f,0.f};

  const int m = wave*16 + l15;
  #pragma unroll
  for (int ks = 0; ks < 5; ++ks) {
    const int G = ks*4 + quad;
    const int slot = (G ^ (m & 7) ^ ((m >> 3) & 7)) << 3;
    const bf16x8 af = *(const bf16x8*)&xt[m*192 + slot];
    #pragma unroll
    for (int ct = 0; ct < 9; ++ct) {
      const bf16x8 bfv = *(const bf16x8*)&As[(ct*16 + l15)*160 + ks*32 + quad*8];
      acc[ct] = __builtin_amdgcn_mfma_f32_16x16x32_bf16(af, bfv, acc[ct], 0, 0, 0);
    }
  }
  __syncthreads();

  #pragma unroll
  for (int ct = 0; ct < 9; ++ct) {
    const int w = ct*16 + l15;
    #pragma unroll
    for (int r = 0; r < 4; ++r) {
      const int c = wave*16 + quad*4 + r;
      ob[w*72 + c] = f2bf(acc[ct][r]);
    }
  }
  __syncthreads();
  {
    const int wl = tid >> 3, cg = tid & 7;
    #pragma unroll
    for (int rr = 0; rr < 5; ++rr) {
      const int w = rr*32 + wl;
      if (w < VV) {
        uint4 val = *(const uint4*)&ob[w*72 + cg*8];
        *(uint4*)(outp + ((size_t)b*NN + (size_t)w*TT + t)*Cfull + ch*64 + cg*8) = val;
      }
    }
  }
}

// ---------------- FC ----------------
__global__ void fc_kernel(const float* __restrict__ mean,
                          const float* __restrict__ fcw,
                          const float* __restrict__ fcb,
                          float* __restrict__ out) {
  const int b = blockIdx.x;
  __shared__ float ms[256];
  const int tid = threadIdx.x;
  ms[tid] = mean[b*256 + tid];
  __syncthreads();
  if (tid < NCLS) {
    float acc = fcb[tid];
    for (int c = 0; c < 256; ++c) acc = fmaf(ms[c], fcw[tid*256 + c], acc);
    out[b*NCLS + tid] = acc;
  }
}

extern "C" void kernel_launch(void* const* d_in, const int* in_sizes, int n_in,
                              void* d_out, int out_size, void* d_ws, size_t ws_size,
                              hipStream_t stream) {
  const float* X    = (const float*)d_in[0];
  const float* bn_g = (const float*)d_in[1];
  const float* bn_b = (const float*)d_in[2];
  const float* w0   = (const float*)d_in[3];
  const float* cb0  = (const float*)d_in[4];
  const float* w1   = (const float*)d_in[5];
  const float* cb1  = (const float*)d_in[6];
  const float* w2   = (const float*)d_in[7];
  const float* cb2  = (const float*)d_in[8];
  const float* w3   = (const float*)d_in[9];
  const float* cb3  = (const float*)d_in[10];
  const float* fcw  = (const float*)d_in[11];
  const float* fcb  = (const float*)d_in[12];
  float* out = (float*)d_out;

  unsigned char* W = (unsigned char*)d_ws;
  size_t off = 0;
  auto alloc = [&](size_t bytes) -> void* {
    void* p = W + off;
    off += (bytes + 255) & ~(size_t)255;
    return p;
  };
  float* meanb  = (float*)alloc(BB*256*4);        // 16 KB
  float* zbuf_f = (float*)alloc(2048);            // 2 KB zero page
  float* scale  = (float*)alloc(512*4);
  float* shiftb = (float*)alloc(512*4);
  unsigned short* w0T = (unsigned short*)alloc(64*32*2);
  unsigned short* wT1 = (unsigned short*)alloc((size_t)9*64*64*2);
  unsigned short* wT2 = (unsigned short*)alloc((size_t)9*128*64*2);
  unsigned short* wT3 = (unsigned short*)alloc((size_t)9*256*128*2);
  unsigned short* xn  = (unsigned short*)alloc((size_t)BB*NN*3*2);
  const size_t fixedB = off;
  const size_t perB = 2*((size_t)NN*128*2 + 256) + ((size_t)TT*APITCH*2 + 256);

  int g = 1;
  if (ws_size > fixedB + perB) {
    size_t gg = (ws_size - fixedB) / perB;
    g = (gg >= BB) ? BB : (int)gg;
  }
  unsigned short* P  = (unsigned short*)alloc((size_t)g*NN*128*2);
  unsigned short* Q  = (unsigned short*)alloc((size_t)g*NN*128*2);
  unsigned short* Ab = (unsigned short*)alloc((size_t)g*TT*APITCH*2);
  const unsigned short* zbuf = (const unsigned short*)zbuf_f;

  bn_stats_kernel<<<411, 256, 0, stream>>>(X, bn_g, bn_b, scale, shiftb);
  bn_apply_v<<<(BB*NN*3 + 255)/256, 256, 0, stream>>>(X, scale, shiftb, xn);
  w0trans_kernel<<<(64*32 + 255)/256, 256, 0, stream>>>(w0, w0T);
  wtrans_kernel<<<(9*64*64   + 255)/256, 256, 0, stream>>>(w1, wT1, 64, 64);
  wtrans_kernel<<<(9*128*64  + 255)/256, 256, 0, stream>>>(w2, wT2, 128, 64);
  wtrans_kernel<<<(9*256*128 + 255)/256, 256, 0, stream>>>(w3, wT3, 256, 128);
  zero_kernel<<<((BB*256 + 512) + 255)/256, 256, 0, stream>>>(meanb, BB*256 + 512);

  for (int b0 = 0; b0 < BB; b0 += g) {
    const int gb = (BB - b0 < g) ? (BB - b0) : g;
    const float* Xg = X + (size_t)b0 * TT * VV * CCH;
    const unsigned short* xng = xn + (size_t)b0 * NN * 3;
    float* mg = meanb + (size_t)b0 * 256;

    adj_v<<<gb*TT, 256, 0, stream>>>(Xg, Ab);
    // conv0: xn(3ch) -> P [n][64]
    conv0_v<<<137*gb, 256, 0, stream>>>(xng, w0T, cb0, P);
    // layer 1: gmm -> Q[n][64]; conv1 (reg-weights) -> P[n][64]
    gmm_v3<<<dim3(gb*TT, 1), 256, 0, stream>>>(Ab, P, Q, 64);
    conv_v4<64,64,1,0><<<137*gb, 256, 0, stream>>>(Q, wT1, cb1, P, nullptr, zbuf, 64, 1);
    // layer 2: gmm -> Q[n][64]; conv2 (reg-weights) -> P[n][128]
    gmm_v3<<<dim3(gb*TT, 1), 256, 0, stream>>>(Ab, P, Q, 64);
    conv_v4<64,128,1,0><<<137*gb, 256, 0, stream>>>(Q, wT2, cb2, P, nullptr, zbuf, 128, 1);
    // layer 3: gmm (128ch, 2 halves) -> Q[n][128]; conv3 (reg-weights, FUSE)
    gmm_v3<<<dim3(gb*TT, 2), 256, 0, stream>>>(Ab, P, Q, 128);
    conv_v4<128,128,1,1><<<137*2*gb, 256, 0, stream>>>(Q, wT3, cb3, nullptr, mg, zbuf, 256, 2);
  }

  fc_kernel<<<BB, 256, 0, stream>>>(meanb, fcw, fcb, out);
}

// Round 15
// 544.455 us; speedup vs baseline: 1.3510x; 1.3510x over previous
//
#include <hip/hip_runtime.h>
#include <hip/hip_bf16.h>
#include <math.h>

#define BB 16
#define TT 128
#define VV 137
#define CCH 3
#define NN (VV*TT)        // 17536 spatial, v-major: n = v*128 + t
#define NCLS 226
#define APITCH 23040      // shorts per (b,t) adjacency slab: [144 w][160 v] = 45 x 1KB

typedef __attribute__((ext_vector_type(8))) short bf16x8;
typedef __attribute__((ext_vector_type(4))) float f32x4;

__device__ __forceinline__ unsigned short f2bf(float x) {
  __hip_bfloat16 h = __float2bfloat16(x);
  return *reinterpret_cast<unsigned short*>(&h);
}

// async 16B direct-to-LDS copy
__device__ __forceinline__ void gld_lds16(const unsigned short* src, unsigned short* ldst) {
  __builtin_amdgcn_global_load_lds(
      (const __attribute__((address_space(1))) void*)src,
      (__attribute__((address_space(3))) void*)ldst, 16, 0, 0);
}

// ---------------- device bodies shared by mega_prep / adj_v ----------------
__device__ void bn_stats_body(const float* __restrict__ X,
                              const float* __restrict__ gamma,
                              const float* __restrict__ beta,
                              float* __restrict__ scale,
                              float* __restrict__ shift,
                              int ch, float* sm) {
  const int v = ch / CCH, c = ch % CCH;
  const int tid = threadIdx.x;
  float s = 0.f, q = 0.f;
  for (int idx = tid; idx < BB*TT; idx += 256) {
    float x = X[(idx*VV + v)*CCH + c];
    s += x; q += x*x;
  }
  #pragma unroll
  for (int off = 32; off > 0; off >>= 1) {
    s += __shfl_down(s, off, 64);
    q += __shfl_down(q, off, 64);
  }
  const int wid = tid >> 6, lane = tid & 63;
  if (lane == 0) { sm[wid] = s; sm[4 + wid] = q; }
  __syncthreads();
  if (tid == 0) {
    float S = sm[0]+sm[1]+sm[2]+sm[3];
    float Q = sm[4]+sm[5]+sm[6]+sm[7];
    const float inv_n = 1.f / (BB*TT);
    float mean = S * inv_n;
    float var = Q * inv_n - mean*mean;
    float sc = gamma[ch] * rsqrtf(var + 1e-5f);
    scale[ch] = sc;
    shift[ch] = beta[ch] - mean * sc;
  }
}

__device__ void adj_body(const float* __restrict__ X, unsigned short* __restrict__ A,
                         int bt, float* XsF) {
  const int b = bt / TT, t = bt % TT;
  const int tid = threadIdx.x;
  for (int i = tid; i < 3*VV; i += 256) {
    const int c = i / VV, v = i % VV;
    XsF[c*144 + v] = X[((b*TT + t)*VV + v)*CCH + c];
  }
  __syncthreads();
  unsigned short* Ab = A + (size_t)bt * APITCH;
  for (int e = tid; e < 144*160; e += 256) {
    const int w = e / 160, v = e % 160;
    unsigned short val = 0;
    if (w < VV && v < VV) {
      const float d0 = XsF[v]       - XsF[w];
      const float d1 = XsF[144 + v] - XsF[144 + w];
      const float d2 = XsF[288 + v] - XsF[288 + w];
      val = f2bf(__expf(-2.f * sqrtf(d0*d0 + d1*d1 + d2*d2)));
    }
    Ab[e] = val;
  }
}

// ---------------- mega_prep: bn_stats + adjacency(first group) + wtrans + zero, one launch ----
// blocks [0,411): bn_stats; [411,411+nadj): adjacency; rest: elementwise pool.
__global__ __launch_bounds__(256)
void mega_prep(const float* __restrict__ X,
               const float* __restrict__ bn_g, const float* __restrict__ bn_b,
               const float* __restrict__ w0, const float* __restrict__ w1,
               const float* __restrict__ w2, const float* __restrict__ w3,
               float* __restrict__ scale, float* __restrict__ shift,
               float* __restrict__ zmem,
               unsigned short* __restrict__ w0T, unsigned short* __restrict__ wT1,
               unsigned short* __restrict__ wT2, unsigned short* __restrict__ wT3,
               unsigned short* __restrict__ A, int nadj) {
  __shared__ float sm[3*144];
  int blk = blockIdx.x;
  if (blk < 411) { bn_stats_body(X, bn_g, bn_b, scale, shift, blk, sm); return; }
  blk -= 411;
  if (blk < nadj) { adj_body(X, A, blk, sm); return; }
  blk -= nadj;
  const int i = blk*256 + threadIdx.x;
  const int NZ = BB*256 + 512;
  if (i < NZ) { zmem[i] = 0.f; return; }
  int o = i - NZ;
  if (o < 64*32) {                       // w0T[oc][k], k=kk*3+ic, pad to 32
    const int k = o & 31, oc = o >> 5;
    const int kk = k / 3, ic = k % 3;
    w0T[o] = (k < 27) ? f2bf(w0[(oc*3 + ic)*9 + kk]) : (unsigned short)0;
    return;
  }
  o -= 64*32;
  if (o < 9*64*64) {                     // wT1[kk][oc64][ic64]
    const int ic = o & 63, oc = (o >> 6) & 63, kk = o >> 12;
    wT1[o] = f2bf(w1[(oc*64 + ic)*9 + kk]); return;
  }
  o -= 9*64*64;
  if (o < 9*128*64) {                    // wT2[kk][oc128][ic64]
    const int ic = o & 63, oc = (o >> 6) & 127, kk = o >> 13;
    wT2[o] = f2bf(w2[(oc*64 + ic)*9 + kk]); return;
  }
  o -= 9*128*64;
  if (o < 9*256*128) {                   // wT3[kk][oc256][ic128]
    const int ic = o & 127, oc = (o >> 7) & 255, kk = o >> 15;
    wT3[o] = f2bf(w3[(oc*128 + ic)*9 + kk]); return;
  }
}

// ---------------- adjacency-only kernel (groups after the first, if g<16) ----------------
__global__ __launch_bounds__(256)
void adj_v(const float* __restrict__ X, unsigned short* __restrict__ A) {
  __shared__ float XsF[3*144];
  adj_body(X, A, blockIdx.x, XsF);
}

// ---------------- conv0: BN folded into im2col; block = one v-row (128 t), K=32 ----------------
__global__ __launch_bounds__(256)
void conv0_v(const float* __restrict__ X,            // [gb][T][V][3] fp32 (group-offset)
             const float* __restrict__ scale,
             const float* __restrict__ shift,
             const unsigned short* __restrict__ w0T, // [64][32]
             const float* __restrict__ bias,
             unsigned short* __restrict__ outp) {    // [gb][NN][64]
  __shared__ unsigned short im_s[128*40];
  __shared__ unsigned short w_s[64*40];
  __shared__ unsigned short ob[128*72];
  const int tid = threadIdx.x;
  const int v0 = blockIdx.x % 137;
  const int b  = blockIdx.x / 137;
  const int wave = tid >> 6, lane = tid & 63, quad = lane >> 4, l15 = lane & 15;
  const int mh = wave * 32;

  {
    const int row = tid >> 2, cg = tid & 3;
    *(uint4*)&w_s[row*40 + cg*8] = *(const uint4*)(w0T + row*32 + cg*8);
  }
  for (int e = tid; e < 128*32; e += 256) {
    const int t = e >> 5, k = e & 31;
    unsigned short val = 0;
    if (k < 27) {
      const int kk = k / 3, ic = k % 3;
      const int tp = t + kk - 4;
      if (tp >= 0 && tp < TT) {
        const float x = X[((size_t)(b*TT + tp)*VV + v0)*3 + ic];
        val = f2bf(x * scale[v0*3 + ic] + shift[v0*3 + ic]);
      }
    }
    im_s[t*40 + k] = val;
  }
  __syncthreads();

  f32x4 acc[2][4];
  #pragma unroll
  for (int mt = 0; mt < 2; ++mt)
    #pragma unroll
    for (int ct = 0; ct < 4; ++ct) acc[mt][ct] = (f32x4){0.f,0.f,0.f,0.f};

  bf16x8 af[2], bfr[4];
  #pragma unroll
  for (int mt = 0; mt < 2; ++mt)
    af[mt] = *(const bf16x8*)&im_s[(mh + mt*16 + l15)*40 + quad*8];
  #pragma unroll
  for (int ct = 0; ct < 4; ++ct)
    bfr[ct] = *(const bf16x8*)&w_s[(ct*16 + l15)*40 + quad*8];
  #pragma unroll
  for (int mt = 0; mt < 2; ++mt)
    #pragma unroll
    for (int ct = 0; ct < 4; ++ct)
      acc[mt][ct] = __builtin_amdgcn_mfma_f32_16x16x32_bf16(af[mt], bfr[ct], acc[mt][ct], 0, 0, 0);

  #pragma unroll
  for (int mt = 0; mt < 2; ++mt) {
    const int tb = mh + mt*16 + quad*4;
    #pragma unroll
    for (int ct = 0; ct < 4; ++ct) {
      const int oc = ct*16 + l15;
      const float bv = bias[oc];
      #pragma unroll
      for (int r = 0; r < 4; ++r)
        ob[(tb + r)*72 + oc] = f2bf(acc[mt][ct][r] + bv);
    }
  }
  __syncthreads();
  for (int rr = 0; rr < 4; ++rr) {
    const int idx = rr*256 + tid;
    const int t = idx >> 3, cg = idx & 7;
    uint4 val = *(const uint4*)&ob[t*72 + cg*8];
    *(uint4*)(outp + ((size_t)b*NN + (size_t)v0*TT + t)*64 + cg*8) = val;
  }
}

// ---------------- conv (K=9 over t), v-major, occupancy-tuned (round-13 proven) ----------------
template<int IC, int OCB, int VROWS, int WDBUF, int RELU, int FUSE>
__global__ __launch_bounds__(256)
void conv_v3(const unsigned short* __restrict__ in,    // [gb][NN][IC]
             const unsigned short* __restrict__ wT,    // [9][OCtot][IC]
             const float* __restrict__ bias,
             unsigned short* __restrict__ outp,        // [gb][NN][OCB] (OCtot==OCB)
             float* __restrict__ mout,
             const unsigned short* __restrict__ zbuf,
             int OCtot, int nocb) {
  constexpr int NCT  = (VROWS == 2) ? OCB/16 : OCB/32;
  constexpr int NWIN = 136*IC/512;
  constexpr int TWIN = VROWS*NWIN;
  constexpr int WWIN = OCB*IC/512;
  constexpr int GPR  = IC/8;
  constexpr int RPW  = 512/IC;
  constexpr int INSZ = VROWS*136*IC;
  constexpr int WSZ  = OCB*IC;
  constexpr int NWB  = WDBUF ? 2 : 1;
  constexpr int OCP  = OCB + 8;
  constexpr int OBSZ = FUSE ? 0 : VROWS*128*OCP;
  constexpr int TOT  = (INSZ + NWB*WSZ > OBSZ) ? (INSZ + NWB*WSZ) : OBSZ;
  __shared__ unsigned short sh[TOT];
  unsigned short* in_s = sh;
  unsigned short* ob = sh;

  const int tid = threadIdx.x;
  const int wave = tid >> 6, lane = tid & 63, quad = lane >> 4, l15 = lane & 15;
  const int nv = (VROWS == 2) ? 69 : 137;
  const int grp  = blockIdx.x % nv;
  const int ocby = (blockIdx.x / nv) % nocb;
  const int b    = blockIdx.x / (nv*nocb);
  const int v0 = grp * VROWS;
  const int ocb0 = ocby * OCB;
  const int vr  = (VROWS == 2) ? (wave >> 1) : 0;
  const int mhl = (VROWS == 2) ? ((wave & 1) * 64) : ((wave >> 1) * 64);
  const int chb = (VROWS == 2) ? 0 : ((wave & 1) * (OCB >> 1));
  const bool vok = (VROWS == 1) || ((v0 + vr) < VV);

  const int lrow = lane / GPR;
  const int lg   = lane % GPR;

  #pragma unroll
  for (int wi = 0; wi < (TWIN+3)/4; ++wi) {
    const int W = wave + 4*wi;
    if (W < TWIN) {
      const int vrW = W / NWIN;
      const int rl = (W % NWIN)*RPW + lrow;
      const int t = rl - 4;
      const int sg = lg ^ (rl & 7);
      const unsigned short* src = (t >= 0 && t < TT && (v0+vrW) < VV)
          ? in + ((size_t)b*NN + (size_t)(v0+vrW)*TT + t)*IC + (sg<<3)
          : zbuf + lane*8;
      gld_lds16(src, in_s + W*512);
    }
  }
  auto stage_w = [&](int kk, int buf) {
    unsigned short* wb = sh + INSZ + buf*WSZ;
    #pragma unroll
    for (int wi = 0; wi < WWIN/4; ++wi) {
      const int W = wave + 4*wi;
      const int row = W*RPW + lrow;
      const int sg = lg ^ (row & 7);
      gld_lds16(wT + ((size_t)kk*OCtot + ocb0 + row)*IC + (sg<<3), wb + W*512);
    }
  };

  f32x4 acc[4][NCT];
  #pragma unroll
  for (int mt = 0; mt < 4; ++mt)
    #pragma unroll
    for (int ct = 0; ct < NCT; ++ct) acc[mt][ct] = (f32x4){0.f,0.f,0.f,0.f};

  auto compute_kk = [&](int kk, int buf) {
    const unsigned short* wb = sh + INSZ + buf*WSZ;
    #pragma unroll
    for (int ks = 0; ks < IC/32; ++ks) {
      const int G = ks*4 + quad;
      bf16x8 af[4], bfr[NCT];
      #pragma unroll
      for (int mt = 0; mt < 4; ++mt) {
        const int row = mhl + mt*16 + l15 + kk;
        af[mt] = *(const bf16x8*)&in_s[vr*(136*IC) + row*IC + ((G ^ (row & 7)) << 3)];
      }
      #pragma unroll
      for (int ct = 0; ct < NCT; ++ct) {
        const int row = chb + ct*16 + l15;
        bfr[ct] = *(const bf16x8*)&wb[row*IC + ((G ^ (row & 7)) << 3)];
      }
      #pragma unroll
      for (int mt = 0; mt < 4; ++mt)
        #pragma unroll
        for (int ct = 0; ct < NCT; ++ct)
          acc[mt][ct] = __builtin_amdgcn_mfma_f32_16x16x32_bf16(af[mt], bfr[ct], acc[mt][ct], 0, 0, 0);
    }
  };

  if (WDBUF) {
    stage_w(0, 0);
    __syncthreads();
    for (int kk = 0; kk < 9; ++kk) {
      if (kk < 8) stage_w(kk+1, (kk+1) & 1);
      compute_kk(kk, kk & 1);
      __syncthreads();
    }
  } else {
    for (int kk = 0; kk < 9; ++kk) {
      stage_w(kk, 0);
      __syncthreads();
      compute_kk(kk, 0);
      __syncthreads();
    }
  }

  if (FUSE) {
    if (vok) {
      #pragma unroll
      for (int ct = 0; ct < NCT; ++ct) {
        const int oc = ocb0 + chb + ct*16 + l15;
        const float bv = bias[oc];
        float s = 0.f;
        #pragma unroll
        for (int mt = 0; mt < 4; ++mt)
          #pragma unroll
          for (int r = 0; r < 4; ++r) {
            float x = acc[mt][ct][r] + bv;
            if (RELU) x = fmaxf(x, 0.f);
            s += x;
          }
        s += __shfl_down(s, 32, 64);
        s += __shfl_down(s, 16, 64);
        if (lane < 16) atomicAdd(&mout[(size_t)b*OCtot + oc], s * (1.f / NN));
      }
    }
  } else {
    #pragma unroll
    for (int mt = 0; mt < 4; ++mt) {
      const int ro = vr*128 + mhl + mt*16 + quad*4;
      #pragma unroll
      for (int ct = 0; ct < NCT; ++ct) {
        const int oc = chb + ct*16 + l15;
        const float bv = bias[ocb0 + oc];
        #pragma unroll
        for (int r = 0; r < 4; ++r) {
          float x = acc[mt][ct][r] + bv;
          if (RELU) x = fmaxf(x, 0.f);
          ob[(ro + r)*OCP + oc] = f2bf(x);
        }
      }
    }
    __syncthreads();
    constexpr int GPO = OCB/8;
    #pragma unroll
    for (int it = 0; it < VROWS*128*GPO/256; ++it) {
      const int task = it*256 + tid;
      const int ro = task / GPO, g = task % GPO;
      const int vrow = v0 + (ro >> 7);
      if (vrow < VV) {
        uint4 val = *(const uint4*)&ob[ro*OCP + g*8];
        *(uint4*)(outp + ((size_t)b*NN + (size_t)vrow*TT + (ro & 127))*OCB + g*8) = val;
      }
    }
  }
}

// ---------------- graph matmul v3: adjacency DMA'd into LDS, ob aliased over As ----------------
__global__ __launch_bounds__(256)
void gmm_v3(const unsigned short* __restrict__ A,     // [gb*T][APITCH]
            const unsigned short* __restrict__ act,
            unsigned short* __restrict__ outp,
            int Cfull) {
  __shared__ unsigned short sh[12288 + APITCH];
  unsigned short* xt = sh;            // X^T[c][v granule-swizzled], 64*192
  unsigned short* As = sh + 12288;    // [144 w][160 v]
  unsigned short* ob = sh + 12288;    // aliases As after compute barrier
  const int bt = blockIdx.x;
  const int b = bt / TT, t = bt % TT;
  const int ch = blockIdx.y;
  const int tid = threadIdx.x;
  const int wave = tid >> 6, lane = tid & 63, quad = lane >> 4, l15 = lane & 15;

  const unsigned short* Abt = A + (size_t)bt * APITCH;
  for (int W = wave; W < 45; W += 4)
    gld_lds16(Abt + W*512 + lane*8, As + W*512);

  #pragma unroll
  for (int it = 0; it < 5; ++it) {
    const int task = it*256 + tid;
    const int v = task >> 3, g = task & 7;
    uint4 val = {0u,0u,0u,0u};
    if (v < VV)
      val = *(const uint4*)(act + ((size_t)b*NN + (size_t)v*TT + t)*Cfull + ch*64 + g*8);
    const unsigned short* pv = (const unsigned short*)&val;
    const int vg = v >> 3, vrm = v & 7;
    #pragma unroll
    for (int j = 0; j < 8; ++j) {
      const int c = g*8 + j;
      const int slot = ((vg ^ (c & 7) ^ ((c >> 3) & 7)) << 3) | vrm;
      xt[c*192 + slot] = pv[j];
    }
  }
  __syncthreads();

  f32x4 acc[9];
  #pragma unroll
  for (int ct = 0; ct < 9; ++ct) acc[ct] = (f32x4){0.f,0.f,0.f,0.f};

  const int m = wave*16 + l15;
  #pragma unroll
  for (int ks = 0; ks < 5; ++ks) {
    const int G = ks*4 + quad;
    const int slot = (G ^ (m & 7) ^ ((m >> 3) & 7)) << 3;
    const bf16x8 af = *(const bf16x8*)&xt[m*192 + slot];
    #pragma unroll
    for (int ct = 0; ct < 9; ++ct) {
      const bf16x8 bfv = *(const bf16x8*)&As[(ct*16 + l15)*160 + ks*32 + quad*8];
      acc[ct] = __builtin_amdgcn_mfma_f32_16x16x32_bf16(af, bfv, acc[ct], 0, 0, 0);
    }
  }
  __syncthreads();

  #pragma unroll
  for (int ct = 0; ct < 9; ++ct) {
    const int w = ct*16 + l15;
    #pragma unroll
    for (int r = 0; r < 4; ++r) {
      const int c = wave*16 + quad*4 + r;
      ob[w*72 + c] = f2bf(acc[ct][r]);
    }
  }
  __syncthreads();
  {
    const int wl = tid >> 3, cg = tid & 7;
    #pragma unroll
    for (int rr = 0; rr < 5; ++rr) {
      const int w = rr*32 + wl;
      if (w < VV) {
        uint4 val = *(const uint4*)&ob[w*72 + cg*8];
        *(uint4*)(outp + ((size_t)b*NN + (size_t)w*TT + t)*Cfull + ch*64 + cg*8) = val;
      }
    }
  }
}

// ---------------- FC ----------------
__global__ void fc_kernel(const float* __restrict__ mean,
                          const float* __restrict__ fcw,
                          const float* __restrict__ fcb,
                          float* __restrict__ out) {
  const int b = blockIdx.x;
  __shared__ float ms[256];
  const int tid = threadIdx.x;
  ms[tid] = mean[b*256 + tid];
  __syncthreads();
  if (tid < NCLS) {
    float acc = fcb[tid];
    for (int c = 0; c < 256; ++c) acc = fmaf(ms[c], fcw[tid*256 + c], acc);
    out[b*NCLS + tid] = acc;
  }
}

extern "C" void kernel_launch(void* const* d_in, const int* in_sizes, int n_in,
                              void* d_out, int out_size, void* d_ws, size_t ws_size,
                              hipStream_t stream) {
  const float* X    = (const float*)d_in[0];
  const float* bn_g = (const float*)d_in[1];
  const float* bn_b = (const float*)d_in[2];
  const float* w0   = (const float*)d_in[3];
  const float* cb0  = (const float*)d_in[4];
  const float* w1   = (const float*)d_in[5];
  const float* cb1  = (const float*)d_in[6];
  const float* w2   = (const float*)d_in[7];
  const float* cb2  = (const float*)d_in[8];
  const float* w3   = (const float*)d_in[9];
  const float* cb3  = (const float*)d_in[10];
  const float* fcw  = (const float*)d_in[11];
  const float* fcb  = (const float*)d_in[12];
  float* out = (float*)d_out;

  unsigned char* W = (unsigned char*)d_ws;
  size_t off = 0;
  auto alloc = [&](size_t bytes) -> void* {
    void* p = W + off;
    off += (bytes + 255) & ~(size_t)255;
    return p;
  };
  float* meanb  = (float*)alloc(BB*256*4);        // 16 KB (zeroed with zbuf: 4608 floats)
  float* zbuf_f = (float*)alloc(2048);            // 2 KB zero page (contiguous after meanb)
  float* scale  = (float*)alloc(512*4);
  float* shiftb = (float*)alloc(512*4);
  unsigned short* w0T = (unsigned short*)alloc(64*32*2);
  unsigned short* wT1 = (unsigned short*)alloc((size_t)9*64*64*2);
  unsigned short* wT2 = (unsigned short*)alloc((size_t)9*128*64*2);
  unsigned short* wT3 = (unsigned short*)alloc((size_t)9*256*128*2);
  const size_t fixedB = off;
  const size_t perB = 2*((size_t)NN*128*2 + 256) + ((size_t)TT*APITCH*2 + 256);

  int g = 1;
  if (ws_size > fixedB + perB) {
    size_t gg = (ws_size - fixedB) / perB;
    g = (gg >= BB) ? BB : (int)gg;
  }
  unsigned short* P  = (unsigned short*)alloc((size_t)g*NN*128*2);
  unsigned short* Q  = (unsigned short*)alloc((size_t)g*NN*128*2);
  unsigned short* Ab = (unsigned short*)alloc((size_t)g*TT*APITCH*2);
  const unsigned short* zbuf = (const unsigned short*)zbuf_f;

  // mega_prep: bn_stats (411) + adjacency for FIRST group (gb0*TT) + elementwise pool (1610)
  const int gb0 = (g < BB) ? g : BB;
  const int nadj = gb0 * TT;
  mega_prep<<<411 + nadj + 1610, 256, 0, stream>>>(
      X, bn_g, bn_b, w0, w1, w2, w3, scale, shiftb, meanb,
      w0T, wT1, wT2, wT3, Ab, nadj);

  for (int b0 = 0; b0 < BB; b0 += g) {
    const int gb = (BB - b0 < g) ? (BB - b0) : g;
    const float* Xg = X + (size_t)b0 * TT * VV * CCH;
    float* mg = meanb + (size_t)b0 * 256;

    if (b0 > 0) adj_v<<<gb*TT, 256, 0, stream>>>(Xg, Ab);
    // conv0 (BN folded): X(3ch fp32) -> P [n][64]
    conv0_v<<<137*gb, 256, 0, stream>>>(Xg, scale, shiftb, w0T, cb0, P);
    // layer 1: gmm -> Q[n][64]; conv1 (1 v-row, wdbuf) -> P[n][64]
    gmm_v3<<<dim3(gb*TT, 1), 256, 0, stream>>>(Ab, P, Q, 64);
    conv_v3<64,64,1,1,1,0><<<137*gb, 256, 0, stream>>>(Q, wT1, cb1, P, nullptr, zbuf, 64, 1);
    // layer 2: gmm -> Q[n][64]; conv2 (1 v-row, wdbuf) -> P[n][128]
    gmm_v3<<<dim3(gb*TT, 1), 256, 0, stream>>>(Ab, P, Q, 64);
    conv_v3<64,128,1,1,1,0><<<137*gb, 256, 0, stream>>>(Q, wT2, cb2, P, nullptr, zbuf, 128, 1);
    // layer 3: gmm (128ch, 2 halves) -> Q[n][128]; conv3 (1 v-row, single wbuf, FUSE)
    gmm_v3<<<dim3(gb*TT, 2), 256, 0, stream>>>(Ab, P, Q, 128);
    conv_v3<128,128,1,0,1,1><<<137*2*gb, 256, 0, stream>>>(Q, wT3, cb3, nullptr, mg, zbuf, 256, 2);
  }

  fc_kernel<<<BB, 256, 0, stream>>>(meanb, fcw, fcb, out);
}